// Round 2
// baseline (872.619 us; speedup 1.0000x reference)
//
#include <hip/hip_runtime.h>

typedef unsigned short ushort_t;
typedef unsigned int uint_t;

typedef __attribute__((ext_vector_type(8))) __bf16 bf16x8;
typedef __attribute__((ext_vector_type(4))) float f32x4;

#define HH 192
#define WW 192
#define HWD (192*192)          // 36864
#define CC 64
#define BB 16

__device__ __forceinline__ ushort_t f2b(float f) {
    uint_t x = __float_as_uint(f);
    uint_t r = x + 0x7fffu + ((x >> 16) & 1u);   // RNE fp32 -> bf16
    return (ushort_t)(r >> 16);
}
__device__ __forceinline__ bf16x8 zero8() {
    uint4 z; z.x = 0; z.y = 0; z.z = 0; z.w = 0;
    return __builtin_bit_cast(bf16x8, z);
}
__device__ __forceinline__ bf16x8 ld8(const ushort_t* p) {
    return __builtin_bit_cast(bf16x8, *(const uint4*)p);
}

// ---------------- kernel 1: Wc[co][ci][u][v] fp32 -> wt[t][co][ci] bf16
__global__ void k_prep(const float* __restrict__ Wc, ushort_t* __restrict__ wt) {
    int i = blockIdx.x * 256 + threadIdx.x;
    if (i < 9 * 64 * 64) {
        int t  = i >> 12;
        int co = (i >> 6) & 63;
        int ci = i & 63;
        wt[i] = f2b(Wc[(co * 64 + ci) * 9 + t]);
    }
}

// ---------------- kernel 2: pooled[b][c] = mean over H*W (fp32)
__global__ void k_pool(const float* __restrict__ x, float* __restrict__ pooled) {
    int c = blockIdx.x, b = blockIdx.y, tid = threadIdx.x;
    const float4* xp = (const float4*)(x + (size_t)(b * 64 + c) * HWD);
    float s = 0.f;
    for (int i = tid; i < HWD / 4; i += 256) {
        float4 u = xp[i];
        s += u.x + u.y + u.z + u.w;
    }
    __shared__ float red[4];
    for (int o = 32; o > 0; o >>= 1) s += __shfl_down(s, o, 64);
    if ((tid & 63) == 0) red[tid >> 6] = s;
    __syncthreads();
    if (tid == 0) pooled[b * 64 + c] = (red[0] + red[1] + red[2] + red[3]) * (1.f / (float)HWD);
}

// ---------------- kernel 3: MLP + channel filter norm -> cf[b][c][t] fp32
__global__ void k_mlp(const float* __restrict__ pooled,
                      const float* __restrict__ W1, const float* __restrict__ b1,
                      const float* __restrict__ W2, const float* __restrict__ b2,
                      const float* __restrict__ std_ch, float* __restrict__ cf) {
    int b = blockIdx.x, tid = threadIdx.x;  // 64 threads
    __shared__ float pl[64], hv[12];
    pl[tid] = pooled[b * 64 + tid];
    __syncthreads();
    if (tid < 12) {
        float h = b1[tid];
        for (int c = 0; c < 64; c++) h += pl[c] * W1[tid * 64 + c];
        hv[tid] = h > 0.f ? h : 0.f;
    }
    __syncthreads();
    int c = tid;
    float r[9]; float m = 0.f;
    #pragma unroll
    for (int t = 0; t < 9; t++) {
        float v = b2[c * 9 + t];
        #pragma unroll
        for (int k = 0; k < 12; k++) v += hv[k] * W2[(c * 9 + t) * 12 + k];
        r[t] = v; m += v;
    }
    m *= (1.f / 9.f);
    float var = 0.f;
    #pragma unroll
    for (int t = 0; t < 9; t++) { float d = r[t] - m; var += d * d; }
    var *= (1.f / 8.f);                     // ddof=1
    float inv = 1.f / (sqrtf(var) + 1e-10f);
    #pragma unroll
    for (int t = 0; t < 9; t++)
        cf[(b * 64 + c) * 9 + t] = (r[t] - m) * inv * std_ch[c * 9 + t];
}

// ---------------- kernel 4: spatial filter sf[b][t][h][w] fp32
__global__ void k_sf(const float* __restrict__ x, const float* __restrict__ Ws,
                     const float* __restrict__ bs, float* __restrict__ sf) {
    int b = blockIdx.y;
    __shared__ float WsL[576];
    __shared__ float bsL[9];
    for (int i = threadIdx.x; i < 576; i += 256) WsL[i] = Ws[i];
    if (threadIdx.x < 9) bsL[threadIdx.x] = bs[threadIdx.x];
    __syncthreads();
    int pg = blockIdx.x * 256 + threadIdx.x;   // [0, 9216) -> 4 pixels each
    int h = pg / 48, w0 = (pg % 48) * 4;
    const float* xb = x + (size_t)b * 64 * HWD + h * WW + w0;
    float s[9][4];
    #pragma unroll
    for (int t = 0; t < 9; t++) {
        float bv = bsL[t];
        #pragma unroll
        for (int j = 0; j < 4; j++) s[t][j] = bv;
    }
    for (int c = 0; c < 64; c++) {
        float4 u = *(const float4*)(xb + (size_t)c * HWD);
        float xv[4] = { u.x, u.y, u.z, u.w };
        #pragma unroll
        for (int t = 0; t < 9; t++) {
            float w = WsL[t * 64 + c];
            #pragma unroll
            for (int j = 0; j < 4; j++) s[t][j] += xv[j] * w;
        }
    }
    size_t base = (size_t)b * 9 * HWD + h * WW + w0;
    #pragma unroll
    for (int j = 0; j < 4; j++) {
        float m = 0.f;
        #pragma unroll
        for (int t = 0; t < 9; t++) m += s[t][j];
        m *= (1.f / 9.f);
        float var = 0.f;
        #pragma unroll
        for (int t = 0; t < 9; t++) { float d = s[t][j] - m; var += d * d; }
        var *= (1.f / 8.f);                 // ddof=1
        float inv = 0.4714045207910317f / (sqrtf(var) + 1e-10f);  // STD_SPATIAL/(s+eps)
        #pragma unroll
        for (int t = 0; t < 9; t++) s[t][j] = (s[t][j] - m) * inv;
    }
    #pragma unroll
    for (int t = 0; t < 9; t++) {
        float4 o; o.x = s[t][0]; o.y = s[t][1]; o.z = s[t][2]; o.w = s[t][3];
        *(float4*)(sf + base + (size_t)t * HWD) = o;
    }
}

// ---------------- kernel 5: DDF mul + leaky relu -> y NHWC bf16
// thread = 4 pixels (along w) x 8 channels
__global__ void k_ddf(const float* __restrict__ x, const float* __restrict__ sf,
                      const float* __restrict__ cf, ushort_t* __restrict__ y) {
    int b = blockIdx.y;
    __shared__ float cfL[576];
    for (int i = threadIdx.x; i < 576; i += 256) cfL[i] = cf[b * 576 + i];
    __syncthreads();
    int tid = threadIdx.x;
    int cg = tid & 7;                         // channel group (8 ch)
    int pg = blockIdx.x * 32 + (tid >> 3);    // [0, 9216) pixel group (4 px)
    int h = pg / 48, w0 = (pg % 48) * 4;

    float cfv[8][9];
    #pragma unroll
    for (int i = 0; i < 8; i++)
        #pragma unroll
        for (int t = 0; t < 9; t++) cfv[i][t] = cfL[(cg * 8 + i) * 9 + t];

    float sfp[9][4];
    const float* sfb = sf + (size_t)b * 9 * HWD + h * WW + w0;
    #pragma unroll
    for (int t = 0; t < 9; t++) {
        float4 u = *(const float4*)(sfb + (size_t)t * HWD);
        sfp[t][0] = u.x; sfp[t][1] = u.y; sfp[t][2] = u.z; sfp[t][3] = u.w;
    }
    bool hu = h > 0, hd = h < HH - 1;
    bool wl = w0 > 0, wr = (w0 + 4) < WW;

    float acc[4][8];
    #pragma unroll
    for (int p = 0; p < 4; p++)
        #pragma unroll
        for (int i = 0; i < 8; i++) acc[p][i] = 0.f;

    for (int i = 0; i < 8; i++) {
        int c = cg * 8 + i;
        const float* xc = x + (size_t)(b * 64 + c) * HWD + h * WW + w0;
        float xn[3][6];
        #pragma unroll
        for (int r = 0; r < 3; r++) {
            bool okr = (r == 1) || (r == 0 ? hu : hd);
            const float* xr = xc + (r - 1) * WW;
            if (okr) {
                float4 u = *(const float4*)xr;
                xn[r][1] = u.x; xn[r][2] = u.y; xn[r][3] = u.z; xn[r][4] = u.w;
                xn[r][0] = wl ? xr[-1] : 0.f;
                xn[r][5] = wr ? xr[4]  : 0.f;
            } else {
                #pragma unroll
                for (int j = 0; j < 6; j++) xn[r][j] = 0.f;
            }
        }
        #pragma unroll
        for (int t = 0; t < 9; t++) {
            const int u_ = t / 3, v_ = t % 3;
            float wct = cfv[i][t];
            #pragma unroll
            for (int p = 0; p < 4; p++)
                acc[p][i] += xn[u_][p + v_] * (wct * sfp[t][p]);
        }
    }
    size_t ybase = ((size_t)(b * HWD + h * WW + w0)) * 64 + cg * 8;
    #pragma unroll
    for (int p = 0; p < 4; p++) {
        ushort_t us[8];
        #pragma unroll
        for (int i = 0; i < 8; i++) {
            float v = acc[p][i];
            v = v >= 0.f ? v : 0.1f * v;      // leaky relu BEFORE conv
            us[i] = f2b(v);
        }
        uint4 o;
        o.x = us[0] | ((uint_t)us[1] << 16);
        o.y = us[2] | ((uint_t)us[3] << 16);
        o.z = us[4] | ((uint_t)us[5] << 16);
        o.w = us[6] | ((uint_t)us[7] << 16);
        *(uint4*)(y + ybase + (size_t)p * 64) = o;
    }
}

// ---------------- kernel 6: 3x3 conv (MFMA bf16) + bias + residual -> out fp32
// A = weights (M=co), B = y pixels (N=16 px), K = ci (2 ksteps of 32 per tap).
// A-frag: A[m=lane&15][k=quad*8+j]; B-frag: B[k=quad*8+j][n=lane&15];
// D: col(n)=lane&15, row(m)=quad*4+reg.
__global__ __launch_bounds__(256, 2)
void k_conv(const ushort_t* __restrict__ y, const ushort_t* __restrict__ wt,
            const float* __restrict__ x, const float* __restrict__ bc,
            float* __restrict__ out) {
    int tid = threadIdx.x;
    int lane = tid & 63, ln = lane & 15, quad = lane >> 4;
    int wid = blockIdx.x * 4 + (tid >> 6);    // 4096 waves
    int phi = wid & 1;
    int g0 = wid >> 1;                        // [0, 2048)

    bf16x8 wf[9][2][2];
    #pragma unroll
    for (int t = 0; t < 9; t++)
        #pragma unroll
        for (int ks = 0; ks < 2; ks++)
            #pragma unroll
            for (int mt = 0; mt < 2; mt++) {
                int co = phi * 32 + mt * 16 + ln;
                wf[t][ks][mt] = ld8(wt + ((t * 64 + co) * 64 + ks * 32 + quad * 8));
            }
    float bcv[2][4];
    #pragma unroll
    for (int mt = 0; mt < 2; mt++)
        #pragma unroll
        for (int r = 0; r < 4; r++)
            bcv[mt][r] = bc[phi * 32 + mt * 16 + quad * 4 + r];

    for (int g = g0; g < BB * HH * (WW / 16); g += 2048) {
        int b = g / (HH * (WW / 16));
        int rem = g - b * (HH * (WW / 16));
        int h = rem / (WW / 16);
        int w0 = (rem % (WW / 16)) * 16;
        f32x4 acc[2];
        #pragma unroll
        for (int mt = 0; mt < 2; mt++) {
            acc[mt][0] = bcv[mt][0]; acc[mt][1] = bcv[mt][1];
            acc[mt][2] = bcv[mt][2]; acc[mt][3] = bcv[mt][3];
        }
        const ushort_t* yb = y + (size_t)b * HWD * 64;
        #pragma unroll
        for (int t = 0; t < 9; t++) {
            const int u_ = t / 3, v_ = t % 3;
            int sh = h + u_ - 1;
            int sw = w0 + ln + v_ - 1;
            bool ok = (sh >= 0) & (sh < HH) & (sw >= 0) & (sw < WW);
            #pragma unroll
            for (int ks = 0; ks < 2; ks++) {
                bf16x8 bfr;
                if (ok) bfr = ld8(yb + (size_t)(sh * WW + sw) * 64 + ks * 32 + quad * 8);
                else    bfr = zero8();
                acc[0] = __builtin_amdgcn_mfma_f32_16x16x32_bf16(wf[t][ks][0], bfr, acc[0], 0, 0, 0);
                acc[1] = __builtin_amdgcn_mfma_f32_16x16x32_bf16(wf[t][ks][1], bfr, acc[1], 0, 0, 0);
            }
        }
        #pragma unroll
        for (int mt = 0; mt < 2; mt++)
            #pragma unroll
            for (int r = 0; r < 4; r++) {
                int co = phi * 32 + mt * 16 + quad * 4 + r;
                size_t off = (size_t)(b * 64 + co) * HWD + h * WW + w0 + ln;
                out[off] = acc[mt][r] + x[off];
            }
    }
}

extern "C" void kernel_launch(void* const* d_in, const int* in_sizes, int n_in,
                              void* d_out, int out_size, void* d_ws, size_t ws_size,
                              hipStream_t stream) {
    const float* x      = (const float*)d_in[0];
    const float* Ws     = (const float*)d_in[1];
    const float* bs     = (const float*)d_in[2];
    const float* W1     = (const float*)d_in[3];
    const float* b1     = (const float*)d_in[4];
    const float* W2     = (const float*)d_in[5];
    const float* b2     = (const float*)d_in[6];
    const float* std_ch = (const float*)d_in[7];
    const float* Wc     = (const float*)d_in[8];
    const float* bc     = (const float*)d_in[9];
    float* out = (float*)d_out;

    char* ws = (char*)d_ws;
    float*    pooled = (float*)(ws);                 // 4 KB
    float*    cf     = (float*)(ws + 4096);          // 36.9 KB
    ushort_t* wt     = (ushort_t*)(ws + 40960);      // 73.7 KB  (ends 114688)
    float*    sf     = (float*)(ws + 131072);        // 21.2 MB  (ends 21364736)
    ushort_t* y      = (ushort_t*)(ws + 21364736);   // 75.5 MB  (ends ~96.9 MB)

    k_prep<<<dim3(144), dim3(256), 0, stream>>>(Wc, wt);
    k_pool<<<dim3(64, 16), dim3(256), 0, stream>>>(x, pooled);
    k_mlp<<<dim3(16), dim3(64), 0, stream>>>(pooled, W1, b1, W2, b2, std_ch, cf);
    k_sf<<<dim3(36, 16), dim3(256), 0, stream>>>(x, Ws, bs, sf);
    k_ddf<<<dim3(288, 16), dim3(256), 0, stream>>>(x, sf, cf, y);
    k_conv<<<dim3(1024), dim3(256), 0, stream>>>(y, wt, x, bc, out);
}

// Round 3
// 611.531 us; speedup vs baseline: 1.4269x; 1.4269x over previous
//
#include <hip/hip_runtime.h>

typedef unsigned short ushort_t;
typedef unsigned int uint_t;

typedef __attribute__((ext_vector_type(8))) __bf16 bf16x8;
typedef __attribute__((ext_vector_type(4))) float f32x4;

#define HH 192
#define WW 192
#define HWD (192*192)          // 36864
#define CC 64
#define BB 16

__device__ __forceinline__ float b2f(uint_t u) {
    return __uint_as_float((u & 0xffffu) << 16);
}
__device__ __forceinline__ ushort_t f2b(float f) {
    uint_t x = __float_as_uint(f);
    uint_t r = x + 0x7fffu + ((x >> 16) & 1u);   // RNE fp32 -> bf16
    return (ushort_t)(r >> 16);
}
__device__ __forceinline__ bf16x8 zero8() {
    uint4 z; z.x = 0; z.y = 0; z.z = 0; z.w = 0;
    return __builtin_bit_cast(bf16x8, z);
}
__device__ __forceinline__ bf16x8 ld8(const ushort_t* p) {
    return __builtin_bit_cast(bf16x8, *(const uint4*)p);
}

// ---------------- kernel 1: Wc[co][ci][u][v] fp32 -> wt[t][co][ci] bf16
__global__ void k_prep(const float* __restrict__ Wc, ushort_t* __restrict__ wt) {
    int i = blockIdx.x * 256 + threadIdx.x;
    if (i < 9 * 64 * 64) {
        int t  = i >> 12;
        int co = (i >> 6) & 63;
        int ci = i & 63;
        wt[i] = f2b(Wc[(co * 64 + ci) * 9 + t]);
    }
}

// ---------------- kernel 2: pooled[b][c] = mean over H*W (fp32)
__global__ void k_pool(const float* __restrict__ x, float* __restrict__ pooled) {
    int c = blockIdx.x, b = blockIdx.y, tid = threadIdx.x;
    const float4* xp = (const float4*)(x + (size_t)(b * 64 + c) * HWD);
    float s = 0.f;
    for (int i = tid; i < HWD / 4; i += 256) {
        float4 u = xp[i];
        s += u.x + u.y + u.z + u.w;
    }
    __shared__ float red[4];
    for (int o = 32; o > 0; o >>= 1) s += __shfl_down(s, o, 64);
    if ((tid & 63) == 0) red[tid >> 6] = s;
    __syncthreads();
    if (tid == 0) pooled[b * 64 + c] = (red[0] + red[1] + red[2] + red[3]) * (1.f / (float)HWD);
}

// ---------------- kernel 3: MLP + channel filter norm -> cf[b][c][t] fp32
__global__ void k_mlp(const float* __restrict__ pooled,
                      const float* __restrict__ W1, const float* __restrict__ b1,
                      const float* __restrict__ W2, const float* __restrict__ b2,
                      const float* __restrict__ std_ch, float* __restrict__ cf) {
    int b = blockIdx.x, tid = threadIdx.x;  // 64 threads
    __shared__ float pl[64], hv[12];
    pl[tid] = pooled[b * 64 + tid];
    __syncthreads();
    if (tid < 12) {
        float h = b1[tid];
        for (int c = 0; c < 64; c++) h += pl[c] * W1[tid * 64 + c];
        hv[tid] = h > 0.f ? h : 0.f;
    }
    __syncthreads();
    int c = tid;
    float r[9]; float m = 0.f;
    #pragma unroll
    for (int t = 0; t < 9; t++) {
        float v = b2[c * 9 + t];
        #pragma unroll
        for (int k = 0; k < 12; k++) v += hv[k] * W2[(c * 9 + t) * 12 + k];
        r[t] = v; m += v;
    }
    m *= (1.f / 9.f);
    float var = 0.f;
    #pragma unroll
    for (int t = 0; t < 9; t++) { float d = r[t] - m; var += d * d; }
    var *= (1.f / 8.f);                     // ddof=1
    float inv = 1.f / (sqrtf(var) + 1e-10f);
    #pragma unroll
    for (int t = 0; t < 9; t++)
        cf[(b * 64 + c) * 9 + t] = (r[t] - m) * inv * std_ch[c * 9 + t];
}

// ---------------- kernel 4: FUSED sf + DDF + leaky -> y NHWC bf16
// Block = 64w x 4h tile, one batch, all 64 channels staged in LDS (bf16).
//   xt[c][row][wh]: row in [0,6) = gh h0-1..h0+4 ; wh in [0,72) = gw w0-4..w0+67
//   c-stride 434 u16 = 217 dwords (odd -> conflict-free lane stride in phase 3)
// Phase 2: thread=pixel, einsum over c + ddof1 norm -> sfL[px][12]
// Phase 3: wave=row, lane=channel; per pixel: 3x3 window from LDS, y store 128B/wave
__global__ __launch_bounds__(256, 2)
void k_fused(const float* __restrict__ x, const float* __restrict__ Ws,
             const float* __restrict__ bs, const float* __restrict__ cf,
             ushort_t* __restrict__ y) {
    __shared__ ushort_t xt[64 * 434];      // 55.5 KB
    __shared__ float sfL[256 * 12];        // 12.3 KB
    __shared__ float WsL[576];
    __shared__ float cfL[576];
    __shared__ float bsL[9];

    int b = blockIdx.y;
    int tw = blockIdx.x % 3, th = blockIdx.x / 3;
    int h0 = th * 4, w0 = tw * 64;
    int tid = threadIdx.x;

    for (int i = tid; i < 576; i += 256) { WsL[i] = Ws[i]; cfL[i] = cf[b * 576 + i]; }
    if (tid < 9) bsL[tid] = bs[tid];

    // ---- phase 1: stage x tile (+halo) as bf16 into LDS
    const float* xb = x + (size_t)b * 64 * HWD;
    #pragma unroll
    for (int j = 0; j < 27; j++) {
        int idx = tid + j * 256;           // [0, 6912)
        int c = idx / 108;
        int rem = idx - c * 108;
        int r = rem / 18, seg = rem - r * 18;
        int gr = h0 - 1 + r;
        int gw0 = w0 - 4 + seg * 4;        // float4-aligned; fully in or out of [0,192)
        float4 v;
        if (gr >= 0 && gr < HH && gw0 >= 0 && gw0 < WW)
            v = *(const float4*)(xb + (size_t)c * HWD + (size_t)gr * WW + gw0);
        else { v.x = 0.f; v.y = 0.f; v.z = 0.f; v.w = 0.f; }
        int o = c * 434 + r * 72 + seg * 4;         // even -> 4B aligned
        *(uint_t*)(&xt[o])     = (uint_t)f2b(v.x) | ((uint_t)f2b(v.y) << 16);
        *(uint_t*)(&xt[o + 2]) = (uint_t)f2b(v.z) | ((uint_t)f2b(v.w) << 16);
    }
    __syncthreads();

    // ---- phase 2: spatial filter for own pixel
    {
        int hl = tid >> 6, wl = tid & 63;
        float s[9];
        #pragma unroll
        for (int t = 0; t < 9; t++) s[t] = bsL[t];
        int base = (hl + 1) * 72 + wl + 4;          // center pixel in halo coords
        for (int c = 0; c < 64; c++) {
            float xv = b2f(xt[c * 434 + base]);
            #pragma unroll
            for (int t = 0; t < 9; t++) s[t] += xv * WsL[t * 64 + c];
        }
        float m = 0.f;
        #pragma unroll
        for (int t = 0; t < 9; t++) m += s[t];
        m *= (1.f / 9.f);
        float var = 0.f;
        #pragma unroll
        for (int t = 0; t < 9; t++) { float d = s[t] - m; var += d * d; }
        var *= (1.f / 8.f);                         // ddof=1
        float inv = 0.4714045207910317f / (sqrtf(var) + 1e-10f);  // STD_SPATIAL/(std+eps)
        #pragma unroll
        for (int t = 0; t < 9; t++) sfL[tid * 12 + t] = (s[t] - m) * inv;
    }
    __syncthreads();

    // ---- phase 3: DDF + leaky relu, lane = channel, wave = row
    int lane = tid & 63;                   // channel
    int hl = tid >> 6;                     // row in tile
    float cfv[9];
    #pragma unroll
    for (int t = 0; t < 9; t++) cfv[t] = cfL[lane * 9 + t];
    const uint_t* lds32 = (const uint_t*)xt;
    int gh = h0 + hl;
    size_t yrow = ((size_t)b * HWD + (size_t)gh * WW + w0) * 64 + lane;

    for (int k = 0; k < 64; k++) {
        const f32x4* sp = (const f32x4*)&sfL[(hl * 64 + k) * 12];
        f32x4 s0 = sp[0], s1 = sp[1];
        float s8 = sfL[(hl * 64 + k) * 12 + 8];
        float wv[9];
        wv[0] = cfv[0] * s0[0]; wv[1] = cfv[1] * s0[1]; wv[2] = cfv[2] * s0[2];
        wv[3] = cfv[3] * s0[3]; wv[4] = cfv[4] * s1[0]; wv[5] = cfv[5] * s1[1];
        wv[6] = cfv[6] * s1[2]; wv[7] = cfv[7] * s1[3]; wv[8] = cfv[8] * s8;

        int p0 = k + 3;                    // first needed wh (window wl+3..wl+5)
        int a = p0 & ~1;
        bool odd = (p0 & 1) != 0;
        float acc = 0.f;
        #pragma unroll
        for (int r = 0; r < 3; r++) {
            int di = lane * 217 + (hl + r) * 36 + (a >> 1);
            uint_t d0 = lds32[di], d1 = lds32[di + 1];
            float v0 = b2f(d0), v1 = b2f(d0 >> 16), v2 = b2f(d1), v3 = b2f(d1 >> 16);
            float xa = odd ? v1 : v0;
            float xm = odd ? v2 : v1;
            float xc = odd ? v3 : v2;
            acc += xa * wv[r * 3 + 0] + xm * wv[r * 3 + 1] + xc * wv[r * 3 + 2];
        }
        float v = acc >= 0.f ? acc : 0.1f * acc;    // leaky BEFORE conv
        y[yrow + (size_t)k * 64] = f2b(v);
    }
}

// ---------------- kernel 6: 3x3 conv (MFMA bf16) + bias + residual -> out fp32
__global__ __launch_bounds__(256, 2)
void k_conv(const ushort_t* __restrict__ y, const ushort_t* __restrict__ wt,
            const float* __restrict__ x, const float* __restrict__ bc,
            float* __restrict__ out) {
    int tid = threadIdx.x;
    int lane = tid & 63, ln = lane & 15, quad = lane >> 4;
    int wid = blockIdx.x * 4 + (tid >> 6);    // 4096 waves
    int phi = wid & 1;
    int g0 = wid >> 1;                        // [0, 2048)

    bf16x8 wf[9][2][2];
    #pragma unroll
    for (int t = 0; t < 9; t++)
        #pragma unroll
        for (int ks = 0; ks < 2; ks++)
            #pragma unroll
            for (int mt = 0; mt < 2; mt++) {
                int co = phi * 32 + mt * 16 + ln;
                wf[t][ks][mt] = ld8(wt + ((t * 64 + co) * 64 + ks * 32 + quad * 8));
            }
    float bcv[2][4];
    #pragma unroll
    for (int mt = 0; mt < 2; mt++)
        #pragma unroll
        for (int r = 0; r < 4; r++)
            bcv[mt][r] = bc[phi * 32 + mt * 16 + quad * 4 + r];

    for (int g = g0; g < BB * HH * (WW / 16); g += 2048) {
        int b = g / (HH * (WW / 16));
        int rem = g - b * (HH * (WW / 16));
        int h = rem / (WW / 16);
        int w0 = (rem % (WW / 16)) * 16;
        f32x4 acc[2];
        #pragma unroll
        for (int mt = 0; mt < 2; mt++) {
            acc[mt][0] = bcv[mt][0]; acc[mt][1] = bcv[mt][1];
            acc[mt][2] = bcv[mt][2]; acc[mt][3] = bcv[mt][3];
        }
        const ushort_t* yb = y + (size_t)b * HWD * 64;
        #pragma unroll
        for (int t = 0; t < 9; t++) {
            const int u_ = t / 3, v_ = t % 3;
            int sh = h + u_ - 1;
            int sw = w0 + ln + v_ - 1;
            bool ok = (sh >= 0) & (sh < HH) & (sw >= 0) & (sw < WW);
            #pragma unroll
            for (int ks = 0; ks < 2; ks++) {
                bf16x8 bfr;
                if (ok) bfr = ld8(yb + (size_t)(sh * WW + sw) * 64 + ks * 32 + quad * 8);
                else    bfr = zero8();
                acc[0] = __builtin_amdgcn_mfma_f32_16x16x32_bf16(wf[t][ks][0], bfr, acc[0], 0, 0, 0);
                acc[1] = __builtin_amdgcn_mfma_f32_16x16x32_bf16(wf[t][ks][1], bfr, acc[1], 0, 0, 0);
            }
        }
        #pragma unroll
        for (int mt = 0; mt < 2; mt++)
            #pragma unroll
            for (int r = 0; r < 4; r++) {
                int co = phi * 32 + mt * 16 + quad * 4 + r;
                size_t off = (size_t)(b * 64 + co) * HWD + h * WW + w0 + ln;
                out[off] = acc[mt][r] + x[off];
            }
    }
}

extern "C" void kernel_launch(void* const* d_in, const int* in_sizes, int n_in,
                              void* d_out, int out_size, void* d_ws, size_t ws_size,
                              hipStream_t stream) {
    const float* x      = (const float*)d_in[0];
    const float* Ws     = (const float*)d_in[1];
    const float* bs     = (const float*)d_in[2];
    const float* W1     = (const float*)d_in[3];
    const float* b1     = (const float*)d_in[4];
    const float* W2     = (const float*)d_in[5];
    const float* b2     = (const float*)d_in[6];
    const float* std_ch = (const float*)d_in[7];
    const float* Wc     = (const float*)d_in[8];
    const float* bc     = (const float*)d_in[9];
    float* out = (float*)d_out;

    char* ws = (char*)d_ws;
    float*    pooled = (float*)(ws);                 // 4 KB
    float*    cf     = (float*)(ws + 4096);          // 36.9 KB
    ushort_t* wt     = (ushort_t*)(ws + 40960);      // 73.7 KB (ends 114688)
    ushort_t* y      = (ushort_t*)(ws + 131072);     // 75.5 MB

    k_prep<<<dim3(144), dim3(256), 0, stream>>>(Wc, wt);
    k_pool<<<dim3(64, 16), dim3(256), 0, stream>>>(x, pooled);
    k_mlp<<<dim3(16), dim3(64), 0, stream>>>(pooled, W1, b1, W2, b2, std_ch, cf);
    k_fused<<<dim3(144, 16), dim3(256), 0, stream>>>(x, Ws, bs, cf, y);
    k_conv<<<dim3(1024), dim3(256), 0, stream>>>(y, wt, x, bc, out);
}